// Round 5
// baseline (131.340 us; speedup 1.0000x reference)
//
#include <hip/hip_runtime.h>
#include <hip/hip_bf16.h>
#include <math.h>

typedef short short8 __attribute__((ext_vector_type(8)));
typedef float floatx4 __attribute__((ext_vector_type(4)));

#define NB 4096
#define DD 128
#define NBLK 256
static constexpr float EPSF = 1e-8f;
static constexpr float TEMP = 11.313708498984760390f; // sqrt(128)

static __device__ __forceinline__ short f2bf(float f) {
    __hip_bfloat16 h = __float2bfloat16(f);
    union { __hip_bfloat16 h; short s; } u; u.h = h; return u.s;
}
static __device__ __forceinline__ float bf2f(short s) {
    union { __hip_bfloat16 h; short s; } u; u.s = s;
    return __bfloat162float(u.h);
}

// Pack 8 consecutive fp32 -> bf16x8 fragment
static __device__ __forceinline__ short8 load_cvt8(const float* __restrict__ p) {
    float4 a = *(const float4*)p;
    float4 b = *(const float4*)(p + 4);
    short8 o;
    o[0] = f2bf(a.x); o[1] = f2bf(a.y); o[2] = f2bf(a.z); o[3] = f2bf(a.w);
    o[4] = f2bf(b.x); o[5] = f2bf(b.y); o[6] = f2bf(b.z); o[7] = f2bf(b.w);
    return o;
}

// Fragment-major offset for qn/kn: matrix row g (0..4095), k index kidx (0..127)
// layout: [g>>4][kidx>>5][(kidx>>3)&3 * 16 + (g&15)][kidx&7]
static __device__ __forceinline__ int frag_off(int g, int kidx) {
    return ((((g >> 4) * 4 + (kidx >> 5)) * 4 + ((kidx >> 3) & 3)) * 16
            + (g & 15)) * 8 + (kidx & 7);
}

// ---------------- fused: proj (phase 1) + grid barrier + scores (phase 2) ---
// 256 blocks x 1024 threads, 1 block/CU (capacity 2/CU -> all 256 blocks
// provably co-resident -> software grid barrier is deadlock-free without
// cooperative launch).
//
// Phase 1: each block runs TWO logical proj units (16 rows x 128 cols, 8
// waves each; waves 0-7 -> unit 2b, waves 8-15 -> unit 2b+1). Identical math
// to the R4-passing proj_kernel.
// Barrier: __syncthreads drains all block stores to L2; thread 0 does an
// AGENT-scope release atomicAdd (L2 writeback on gfx950) and acquire-spins
// to 256 (L1+L2 invalidate); __syncthreads releases the block. Cross-XCD
// safe per guide G16.
// Phase 2: byte-identical to the R4-passing score_rows.
__global__ __launch_bounds__(1024, 4) void fused_kernel(
    const float* __restrict__ qp, const float* __restrict__ kp,
    const float* __restrict__ Wq, const float* __restrict__ bq,
    const float* __restrict__ Wk, const float* __restrict__ bk,
    __hip_bfloat16* __restrict__ qn, __hip_bfloat16* __restrict__ kn,
    float* __restrict__ rq, float* __restrict__ rk,
    float* __restrict__ P, unsigned* __restrict__ ctr)
{
    int tid  = threadIdx.x;
    int lane = tid & 63;
    int wid  = tid >> 6;                // 0..15
    int m    = lane & 15;
    int quad = lane >> 4;

    __shared__ float buf[2][8][16];
    __shared__ float nfb[2][16];

    // ======================= phase 1: projection ===========================
    {
        int g    = wid >> 3;            // which logical unit in this block
        int wid8 = wid & 7;             // wave index within unit
        int u    = blockIdx.x * 2 + g;  // 0..511; 256 per matrix

        int which = u >> 8;
        int row0 = (u & 255) * 16;
        const float* x    = which ? kp : qp;
        const float* W    = which ? Wk : Wq;
        const float* bias = which ? bk : bq;
        short* outv = which ? (short*)kn : (short*)qn;
        float* outr = which ? rk : rq;

        int colb = wid8 * 16;           // wave col origin (8 waves x 16 cols)

        floatx4 acc = (floatx4){0.f, 0.f, 0.f, 0.f};

        #pragma unroll
        for (int ks = 0; ks < 4; ++ks) {
            int koff = ks * 32 + quad * 8;
            short8 af  = load_cvt8(x + (row0 + m) * DD + koff);
            short8 bfr = load_cvt8(W + (colb + m) * DD + koff);
            acc = __builtin_amdgcn_mfma_f32_16x16x32_bf16(af, bfr, acc, 0, 0, 0);
        }

        float bv = bias[colb + m];

        // add bias; per-row sum of squares (this wave's 16 cols)
        #pragma unroll
        for (int r = 0; r < 4; ++r) {
            float v = acc[r] + bv;
            acc[r] = v;
            float p = v * v;
            p += __shfl_xor(p, 1); p += __shfl_xor(p, 2);
            p += __shfl_xor(p, 4); p += __shfl_xor(p, 8);
            if (m == 0) buf[g][wid8][quad*4 + r] = p;
        }
        __syncthreads();
        if (wid8 == 0 && lane < 16) {
            float s = 0.f;
            #pragma unroll
            for (int w = 0; w < 8; ++w) s += buf[g][w][lane];
            float fro = sqrtf(s*s*(1.0f/16384.0f) + s*(1.0f/64.0f) + 128.0f);
            float qnorm = sqrtf((s*s*(1.0f/128.0f) + s) / (fro + EPSF));
            nfb[g][lane] = 1.0f / (qnorm + EPSF);
        }
        __syncthreads();

        // scale, round to bf16, store (fragment-major); row-sum of rounded sq
        #pragma unroll
        for (int r = 0; r < 4; ++r) {
            int lrow = quad*4 + r;          // unit-local 0..15
            int gg = row0 + lrow;           // global matrix row
            float nf = nfb[g][lrow];
            float v = acc[r] * nf;
            short sb = f2bf(v);
            outv[frag_off(gg, colb + m)] = sb;
            float vf = bf2f(sb);
            float u2 = vf * vf;
            u2 += __shfl_xor(u2, 1); u2 += __shfl_xor(u2, 2);
            u2 += __shfl_xor(u2, 4); u2 += __shfl_xor(u2, 8);
            if (m == 0) buf[g][wid8][lrow] = u2;
        }
        __syncthreads();
        if (wid8 == 0 && lane < 16) {
            float s = 0.f;
            #pragma unroll
            for (int w = 0; w < 8; ++w) s += buf[g][w][lane];
            outr[row0 + lane] = s;
        }
    }

    // ======================= grid barrier ==================================
    __syncthreads();                    // drain this block's global stores
    if (tid == 0) {
        __hip_atomic_fetch_add(ctr, 1u, __ATOMIC_RELEASE,
                               __HIP_MEMORY_SCOPE_AGENT);
        while (__hip_atomic_load(ctr, __ATOMIC_ACQUIRE,
                                 __HIP_MEMORY_SCOPE_AGENT) < (unsigned)NBLK) {
            __builtin_amdgcn_s_sleep(2);
        }
    }
    __syncthreads();                    // all threads see phase-1 data

    // ======================= phase 2: scores ===============================
    int rowblk = blockIdx.x;            // 16 rows per block
    int r0 = rowblk * 16;
    int cs = wid * 256;                 // wave's column strip

    const short* qs  = (const short*)qn;
    const short* kks = (const short*)kn;

    // A fragments: 16 rows x K=128 (coalesced 1 KB loads)
    short8 af[4];
    #pragma unroll
    for (int k4 = 0; k4 < 4; ++k4)
        af[k4] = *(const short8*)(qs + ((rowblk*4 + k4)*64 + lane)*8);

    float rqv = rq[r0 + m];             // this lane's q-row |qn|^2

    floatx4 acc[4][4];                  // e values: 16 rows x 256 cols / 64 lanes
    float rs = 0.f;                     // partial row sum for row r0+m

    #pragma unroll
    for (int it = 0; it < 4; ++it) {
        #pragma unroll
        for (int ct = 0; ct < 4; ++ct) {
            int colblk = (cs >> 4) + it*4 + ct;
            short8 bfr[4];
            #pragma unroll
            for (int k4 = 0; k4 < 4; ++k4)
                bfr[k4] = *(const short8*)(kks + ((colblk*4 + k4)*64 + lane)*8);
            floatx4 a = (floatx4){0.f, 0.f, 0.f, 0.f};
            #pragma unroll
            for (int k4 = 0; k4 < 4; ++k4)
                a = __builtin_amdgcn_mfma_f32_16x16x32_bf16(bfr[k4], af[k4], a, 0, 0, 0);
            // lane holds: q-row r0+m, k-cols colblk*16 + quad*4 + r
            floatx4 rkv = *(const floatx4*)(rk + colblk*16 + quad*4);
            #pragma unroll
            for (int r = 0; r < 4; ++r) {
                float d2 = fmaf(-2.0f, a[r], rqv + rkv[r]);
                float d  = d2 > 0.0f ? __builtin_amdgcn_sqrtf(d2) : 0.0f;
                float e  = __expf(TEMP * __builtin_amdgcn_rcpf(1.0f + d));
                a[r] = e;
                rs += e;
            }
            acc[it][ct] = a;
        }
    }

    // rs is partial over this lane's 64 cols; reduce across the 4 quads
    rs += __shfl_xor(rs, 16);
    rs += __shfl_xor(rs, 32);

    __shared__ float sums[16][16];
    __shared__ float inv[16];
    if (lane < 16) sums[wid][lane] = rs;   // quad==0 lanes: m = lane
    __syncthreads();
    if (tid < 16) {
        float s = 0.f;
        #pragma unroll
        for (int w = 0; w < 16; ++w) s += sums[w][tid];
        inv[tid] = __builtin_amdgcn_rcpf(s + EPSF);
    }
    __syncthreads();

    float invv = inv[m];

    // float4 stores: lane writes 4 consecutive cols of its row.
    #pragma unroll
    for (int it = 0; it < 4; ++it) {
        #pragma unroll
        for (int ct = 0; ct < 4; ++ct) {
            floatx4 o = acc[it][ct] * invv;
            *(floatx4*)(P + (size_t)(r0 + m) * NB
                          + cs + it*64 + ct*16 + quad*4) = o;
        }
    }
}

extern "C" void kernel_launch(void* const* d_in, const int* in_sizes, int n_in,
                              void* d_out, int out_size, void* d_ws, size_t ws_size,
                              hipStream_t stream) {
    const float* qp = (const float*)d_in[0];
    const float* kp = (const float*)d_in[1];
    const float* Wq = (const float*)d_in[2];
    const float* bq = (const float*)d_in[3];
    const float* Wk = (const float*)d_in[4];
    const float* bk = (const float*)d_in[5];
    float* P = (float*)d_out;

    char* ws = (char*)d_ws;
    __hip_bfloat16* qn = (__hip_bfloat16*)ws;                         // 1 MB
    __hip_bfloat16* kn = (__hip_bfloat16*)(ws + (size_t)NB*DD*2);     // 1 MB
    float* rq = (float*)(ws + (size_t)NB*DD*4);                       // 16 KB
    float* rk = (float*)(ws + (size_t)NB*DD*4 + (size_t)NB*4);        // 16 KB
    unsigned* ctr = (unsigned*)(ws + (size_t)NB*DD*4 + (size_t)NB*8); // 4 B

    // ws is poisoned each iteration by the harness -> zero the barrier
    // counter first (stream-ordered, graph-capturable; same primitive the
    // harness's own poison fills use).
    hipMemsetAsync(ctr, 0, sizeof(unsigned), stream);

    hipLaunchKernelGGL(fused_kernel, dim3(NBLK), dim3(1024), 0, stream,
                       qp, kp, Wq, bq, Wk, bk, qn, kn, rq, rk, P, ctr);
}

// Round 6
// 125.674 us; speedup vs baseline: 1.0451x; 1.0451x over previous
//
#include <hip/hip_runtime.h>
#include <hip/hip_bf16.h>
#include <math.h>

typedef short short8 __attribute__((ext_vector_type(8)));
typedef float floatx4 __attribute__((ext_vector_type(4)));

#define NB 4096
#define DD 128
static constexpr float EPSF = 1e-8f;
static constexpr float TEMP = 11.313708498984760390f; // sqrt(128)

static __device__ __forceinline__ short f2bf(float f) {
    __hip_bfloat16 h = __float2bfloat16(f);
    union { __hip_bfloat16 h; short s; } u; u.h = h; return u.s;
}
static __device__ __forceinline__ float bf2f(short s) {
    union { __hip_bfloat16 h; short s; } u; u.s = s;
    return __bfloat162float(u.h);
}

// Pack 8 consecutive fp32 -> bf16x8 fragment
static __device__ __forceinline__ short8 load_cvt8(const float* __restrict__ p) {
    float4 a = *(const float4*)p;
    float4 b = *(const float4*)(p + 4);
    short8 o;
    o[0] = f2bf(a.x); o[1] = f2bf(a.y); o[2] = f2bf(a.z); o[3] = f2bf(a.w);
    o[4] = f2bf(b.x); o[5] = f2bf(b.y); o[6] = f2bf(b.z); o[7] = f2bf(b.w);
    return o;
}

// Fragment-major offset for qn/kn: matrix row g (0..4095), k index kidx (0..127)
// layout: [g>>4][kidx>>5][(kidx>>3)&3 * 16 + (g&15)][kidx&7]
// => a wave's MFMA fragment load (lane = quad*16+m, 8 bf16) is 64 consecutive
//    16 B chunks = one fully-coalesced 1 KB load.
static __device__ __forceinline__ int frag_off(int g, int kidx) {
    return ((((g >> 4) * 4 + (kidx >> 5)) * 4 + ((kidx >> 3) & 3)) * 16
            + (g & 15)) * 8 + (kidx & 7);
}

// ---------------- projection + metric-normalize (MFMA, bf16) ----------------
// R4-passing version, unchanged. 512 blocks x 512 threads: 16 rows x 128 cols;
// 8 waves of 16x16; 2 blocks/CU -> 4 waves/SIMD.
__global__ __launch_bounds__(512) void proj_kernel(
    const float* __restrict__ qp, const float* __restrict__ kp,
    const float* __restrict__ Wq, const float* __restrict__ bq,
    const float* __restrict__ Wk, const float* __restrict__ bk,
    __hip_bfloat16* __restrict__ qn, __hip_bfloat16* __restrict__ kn,
    float* __restrict__ rq, float* __restrict__ rk)
{
    int t = threadIdx.x;
    int b = blockIdx.x;                 // 0..511; 256 per matrix

    int which = b >> 8;
    int row0 = (b & 255) * 16;
    const float* x    = which ? kp : qp;
    const float* W    = which ? Wk : Wq;
    const float* bias = which ? bk : bq;
    short* outv = which ? (short*)kn : (short*)qn;
    float* outr = which ? rk : rq;

    int lane = t & 63, wid = t >> 6;    // 8 waves
    int m = lane & 15, quad = lane >> 4;
    int colb = wid * 16;                // wave col origin (8 waves x 16 cols)

    floatx4 acc = (floatx4){0.f, 0.f, 0.f, 0.f};

    #pragma unroll
    for (int ks = 0; ks < 4; ++ks) {
        int koff = ks * 32 + quad * 8;
        short8 af  = load_cvt8(x + (row0 + m) * DD + koff);
        short8 bfr = load_cvt8(W + (colb + m) * DD + koff);
        acc = __builtin_amdgcn_mfma_f32_16x16x32_bf16(af, bfr, acc, 0, 0, 0);
    }

    __shared__ float buf[8][16];
    __shared__ float nfb[16];

    float bv = bias[colb + m];

    // add bias; per-row sum of squares (this wave's 16 cols), reduce over m
    #pragma unroll
    for (int r = 0; r < 4; ++r) {
        float v = acc[r] + bv;
        acc[r] = v;
        float p = v * v;
        p += __shfl_xor(p, 1); p += __shfl_xor(p, 2);
        p += __shfl_xor(p, 4); p += __shfl_xor(p, 8);
        if (m == 0) buf[wid][quad*4 + r] = p;
    }
    __syncthreads();
    if (t < 16) {
        float s = 0.f;
        #pragma unroll
        for (int w = 0; w < 8; ++w) s += buf[w][t];
        float fro = sqrtf(s*s*(1.0f/16384.0f) + s*(1.0f/64.0f) + 128.0f);
        float qnorm = sqrtf((s*s*(1.0f/128.0f) + s) / (fro + EPSF));
        nfb[t] = 1.0f / (qnorm + EPSF);
    }
    __syncthreads();

    // scale, round to bf16, store (fragment-major); row-sum of rounded squares
    #pragma unroll
    for (int r = 0; r < 4; ++r) {
        int lrow = quad*4 + r;              // block-local 0..15
        int g = row0 + lrow;                // global matrix row
        float nf = nfb[lrow];
        float v = acc[r] * nf;
        short sb = f2bf(v);
        outv[frag_off(g, colb + m)] = sb;
        float vf = bf2f(sb);
        float u = vf * vf;
        u += __shfl_xor(u, 1); u += __shfl_xor(u, 2);
        u += __shfl_xor(u, 4); u += __shfl_xor(u, 8);
        if (m == 0) buf[wid][lrow] = u;
    }
    __syncthreads();
    if (t < 16) {
        float s = 0.f;
        #pragma unroll
        for (int w = 0; w < 8; ++w) s += buf[w][t];
        outr[row0 + t] = s;
    }
}

// ---------------- scores: two-pass recompute, no e-accumulator --------------
// 256 blocks x 1024 threads (16 waves, 1 block/CU). Wave w owns cols
// [w*256, w*256+256). Swapped MFMA operands: mfma(bfr, af) -> lane (m,quad)
// owns q-row (r0+m) and 4 consecutive k-cols.
//
// R5 post-mortem: holding all 64 e-values/lane consumed the ENTIRE 128-reg
// budget (64 VGPR + 64 AGPR), leaving zero prefetch headroom -> every tile's
// bfr load latency fully exposed (MfmaUtil 2.9%, VALUBusy 14%, ~80% stall).
// Fix: pass A computes only the row sums (e discarded -> ~60 regs live, so
// the compiler can keep 3-4 tiles of bfr loads in flight); pass B RECOMPUTES
// the bit-identical e (same inputs, same op order) and stores e*invv
// directly. Doubled MFMA+VALU (~3 us) removes the ~40 us latency stall.
// Pass B's kn reads are L2-hot from pass A.
__global__ __launch_bounds__(1024, 4) void score_rows(
    const __hip_bfloat16* __restrict__ qn, const __hip_bfloat16* __restrict__ kn,
    const float* __restrict__ rq, const float* __restrict__ rk,
    float* __restrict__ P)
{
    int lane = threadIdx.x & 63;
    int wid  = threadIdx.x >> 6;        // 0..15
    int m    = lane & 15;
    int quad = lane >> 4;

    int rowblk = blockIdx.x;            // 16 rows per block
    int r0 = rowblk * 16;
    int cs = wid * 256;                 // wave's column strip

    const short* qs  = (const short*)qn;
    const short* kks = (const short*)kn;

    // A fragments: 16 rows x K=128 (coalesced 1 KB loads)
    short8 af[4];
    #pragma unroll
    for (int k4 = 0; k4 < 4; ++k4)
        af[k4] = *(const short8*)(qs + ((rowblk*4 + k4)*64 + lane)*8);

    float rqv = rq[r0 + m];             // this lane's q-row |qn|^2

    // ---------------- pass A: row sums only (e discarded) ----------------
    float rs = 0.f;
    #pragma unroll
    for (int it = 0; it < 4; ++it) {
        #pragma unroll
        for (int ct = 0; ct < 4; ++ct) {
            int colblk = (cs >> 4) + it*4 + ct;
            short8 bfr[4];
            #pragma unroll
            for (int k4 = 0; k4 < 4; ++k4)
                bfr[k4] = *(const short8*)(kks + ((colblk*4 + k4)*64 + lane)*8);
            floatx4 a = (floatx4){0.f, 0.f, 0.f, 0.f};
            #pragma unroll
            for (int k4 = 0; k4 < 4; ++k4)
                a = __builtin_amdgcn_mfma_f32_16x16x32_bf16(bfr[k4], af[k4], a, 0, 0, 0);
            floatx4 rkv = *(const floatx4*)(rk + colblk*16 + quad*4);
            #pragma unroll
            for (int r = 0; r < 4; ++r) {
                float d2 = fmaf(-2.0f, a[r], rqv + rkv[r]);
                float d  = d2 > 0.0f ? __builtin_amdgcn_sqrtf(d2) : 0.0f;
                float e  = __expf(TEMP * __builtin_amdgcn_rcpf(1.0f + d));
                rs += e;
            }
        }
    }

    // rs is partial over this lane's 64 cols; reduce across the 4 quads
    rs += __shfl_xor(rs, 16);
    rs += __shfl_xor(rs, 32);

    __shared__ float sums[16][16];
    __shared__ float inv[16];
    if (lane < 16) sums[wid][lane] = rs;   // quad==0 lanes: m = lane
    __syncthreads();
    if (threadIdx.x < 16) {
        float s = 0.f;
        #pragma unroll
        for (int w = 0; w < 16; ++w) s += sums[w][threadIdx.x];
        inv[threadIdx.x] = __builtin_amdgcn_rcpf(s + EPSF);
    }
    __syncthreads();

    float invv = inv[m];

    // ---------------- pass B: recompute e, scale, store ------------------
    // Same inputs + same op order as pass A -> bit-identical e.
    #pragma unroll
    for (int it = 0; it < 4; ++it) {
        #pragma unroll
        for (int ct = 0; ct < 4; ++ct) {
            int colblk = (cs >> 4) + it*4 + ct;
            short8 bfr[4];
            #pragma unroll
            for (int k4 = 0; k4 < 4; ++k4)
                bfr[k4] = *(const short8*)(kks + ((colblk*4 + k4)*64 + lane)*8);
            floatx4 a = (floatx4){0.f, 0.f, 0.f, 0.f};
            #pragma unroll
            for (int k4 = 0; k4 < 4; ++k4)
                a = __builtin_amdgcn_mfma_f32_16x16x32_bf16(bfr[k4], af[k4], a, 0, 0, 0);
            floatx4 rkv = *(const floatx4*)(rk + colblk*16 + quad*4);
            floatx4 o;
            #pragma unroll
            for (int r = 0; r < 4; ++r) {
                float d2 = fmaf(-2.0f, a[r], rqv + rkv[r]);
                float d  = d2 > 0.0f ? __builtin_amdgcn_sqrtf(d2) : 0.0f;
                float e  = __expf(TEMP * __builtin_amdgcn_rcpf(1.0f + d));
                o[r] = e * invv;
            }
            *(floatx4*)(P + (size_t)(r0 + m) * NB
                          + cs + it*64 + ct*16 + quad*4) = o;
        }
    }
}

extern "C" void kernel_launch(void* const* d_in, const int* in_sizes, int n_in,
                              void* d_out, int out_size, void* d_ws, size_t ws_size,
                              hipStream_t stream) {
    const float* qp = (const float*)d_in[0];
    const float* kp = (const float*)d_in[1];
    const float* Wq = (const float*)d_in[2];
    const float* bq = (const float*)d_in[3];
    const float* Wk = (const float*)d_in[4];
    const float* bk = (const float*)d_in[5];
    float* P = (float*)d_out;

    char* ws = (char*)d_ws;
    __hip_bfloat16* qn = (__hip_bfloat16*)ws;                         // 1 MB
    __hip_bfloat16* kn = (__hip_bfloat16*)(ws + (size_t)NB*DD*2);     // 1 MB
    float* rq = (float*)(ws + (size_t)NB*DD*4);                       // 16 KB
    float* rk = (float*)(ws + (size_t)NB*DD*4 + (size_t)NB*4);        // 16 KB

    hipLaunchKernelGGL(proj_kernel, dim3(512), dim3(512), 0, stream,
                       qp, kp, Wq, bq, Wk, bk, qn, kn, rq, rk);
    hipLaunchKernelGGL(score_rows, dim3(256), dim3(1024), 0, stream,
                       qn, kn, rq, rk, P);
}